// Round 13
// baseline (79.788 us; speedup 1.0000x reference)
//
#include <hip/hip_runtime.h>

#define N_PTS   4096
#define N_BATCH 16
#define INV_CNT (1.0f / (2.0f * N_BATCH * N_PTS))
#define AROW_BYTES ((size_t)2 * N_BATCH * N_PTS * 16 * 2)   // 4 MB
#define SLACK   16384              // ring overshoot landing zone
#define NBLK    512                // main-kernel blocks

typedef _Float16 f16x8  __attribute__((ext_vector_type(8)));

// 32x32x16 f16 MFMA, K-slot packing (split o = oh + ol, p = ph + pl in f16):
//   A-row (opposite point o): [-2oh_x,-2oh_y,-2oh_z, -2ol_x,-2ol_y,-2ol_z,
//                              -2oh_x,-2oh_y | -2oh_z, o2h, o2l, 0...]
//   B-col (query p):          [ph_x,ph_y,ph_z, ph_x,ph_y,ph_z, pl_x,pl_y |
//                              pl_z, 1, 1, 0...]
//   => C = |o|^2 - 2 o.p   (dropped ol.pl ~2^-22; verified R5-R12, absmax 0.0)
// A lane layout: row=l&31, k=(l>>5)*8+j -> one contiguous 16 B load per lane.
__global__ __launch_bounds__(256) void prep_kernel(
    const float* __restrict__ tpl, const float* __restrict__ src,
    _Float16* __restrict__ arow, float* __restrict__ out) {
    int pt = blockIdx.x * 256 + threadIdx.x;          // 0..131071 (T set, then S set)
    if (pt == 0) out[0] = 0.0f;                       // fallback path runs after
    const float* p = (pt < 65536 ? tpl : src) + (size_t)(pt & 65535) * 3;
    float x = p[0], y = p[1], z = p[2];
    float o2 = fmaf(x, x, fmaf(y, y, z * z));
    _Float16 xh = (_Float16)x, yh = (_Float16)y, zh = (_Float16)z;
    _Float16 xl = (_Float16)(x - (float)xh);
    _Float16 yl = (_Float16)(y - (float)yh);
    _Float16 zl = (_Float16)(z - (float)zh);
    _Float16 o2h = (_Float16)o2;
    _Float16 o2l = (_Float16)(o2 - (float)o2h);
    const _Float16 m2 = (_Float16)-2.0f;              // exact power-of-2 scale
    f16x8 v0, v1;
    v0[0] = m2 * xh; v0[1] = m2 * yh; v0[2] = m2 * zh;
    v0[3] = m2 * xl; v0[4] = m2 * yl; v0[5] = m2 * zl;
    v0[6] = m2 * xh; v0[7] = m2 * yh;
    v1[0] = m2 * zh; v1[1] = o2h; v1[2] = o2l;
    v1[3] = (_Float16)0.0f; v1[4] = (_Float16)0.0f; v1[5] = (_Float16)0.0f;
    v1[6] = (_Float16)0.0f; v1[7] = (_Float16)0.0f;
    *(f16x8*)(arow + (size_t)pt * 16)     = v0;
    *(f16x8*)(arow + (size_t)pt * 16 + 8) = v1;
}

// ---- asm blocks. Pinned: A-banks F0..F3 = v[32:47],[48:63],[64:79],[80:95];
//      B-banks F0..F3 = v[96:111],[112:127],[128:143],[144:159];
//      zero-C = v[160:175] (zeroed once). Deferred fold: tile t's D folded
//      during tile t+1 (~80 cyc distance, RAW-safe -- R12-proven scheme). ----
#define FD(a,x,y) "v_min3_f32 %[" #a "], v" #x ", v" #y ", %[" #a "]\n\t"
#define FOLD_A \
  FD(acc0,32,33)  FD(acc1,34,35)  FD(acc0,36,37)  FD(acc1,38,39)  \
  FD(acc0,40,41)  FD(acc1,42,43)  FD(acc0,44,45)  FD(acc1,46,47)  \
  FD(acc2,48,49)  FD(acc3,50,51)  FD(acc2,52,53)  FD(acc3,54,55)  \
  FD(acc2,56,57)  FD(acc3,58,59)  FD(acc2,60,61)  FD(acc3,62,63)  \
  FD(acc4,64,65)  FD(acc5,66,67)  FD(acc4,68,69)  FD(acc5,70,71)  \
  FD(acc4,72,73)  FD(acc5,74,75)  FD(acc4,76,77)  FD(acc5,78,79)  \
  FD(acc6,80,81)  FD(acc7,82,83)  FD(acc6,84,85)  FD(acc7,86,87)  \
  FD(acc6,88,89)  FD(acc7,90,91)  FD(acc6,92,93)  FD(acc7,94,95)
#define FOLD_B \
  FD(acc0,96,97)   FD(acc1,98,99)   FD(acc0,100,101) FD(acc1,102,103) \
  FD(acc0,104,105) FD(acc1,106,107) FD(acc0,108,109) FD(acc1,110,111) \
  FD(acc2,112,113) FD(acc3,114,115) FD(acc2,116,117) FD(acc3,118,119) \
  FD(acc2,120,121) FD(acc3,122,123) FD(acc2,124,125) FD(acc3,126,127) \
  FD(acc4,128,129) FD(acc5,130,131) FD(acc4,132,133) FD(acc5,134,135) \
  FD(acc4,136,137) FD(acc5,138,139) FD(acc4,140,141) FD(acc5,142,143) \
  FD(acc6,144,145) FD(acc7,146,147) FD(acc6,148,149) FD(acc7,150,151) \
  FD(acc6,152,153) FD(acc7,154,155) FD(acc6,156,157) FD(acc7,158,159)
#define MFA(s) \
  "v_mfma_f32_32x32x16_f16 v[32:47], %["  #s "], %[bf0], v[160:175]\n\t" \
  "v_mfma_f32_32x32x16_f16 v[48:63], %["  #s "], %[bf1], v[160:175]\n\t" \
  "v_mfma_f32_32x32x16_f16 v[64:79], %["  #s "], %[bf2], v[160:175]\n\t" \
  "v_mfma_f32_32x32x16_f16 v[80:95], %["  #s "], %[bf3], v[160:175]\n\t"
#define MFB(s) \
  "v_mfma_f32_32x32x16_f16 v[96:111],  %[" #s "], %[bf0], v[160:175]\n\t" \
  "v_mfma_f32_32x32x16_f16 v[112:127], %[" #s "], %[bf1], v[160:175]\n\t" \
  "v_mfma_f32_32x32x16_f16 v[128:143], %[" #s "], %[bf2], v[160:175]\n\t" \
  "v_mfma_f32_32x32x16_f16 v[144:159], %[" #s "], %[bf3], v[160:175]\n\t"
#define LD(s,off) "global_load_dwordx4 %[" #s "], %[voff], %[sb] offset:" #off "\n\t"
// even tile: write A banks, fold B banks (prev tile); odd tile: the reverse
#define TILE_E(s,off) "s_waitcnt vmcnt(7)\n\t" MFA(s) LD(s,off) FOLD_B
#define TILE_O(s,off) "s_waitcnt vmcnt(7)\n\t" MFB(s) LD(s,off) FOLD_A
#define ZM(r)  "v_mov_b32 v" #r ", 0\n\t"
#define IM(r)  "v_mov_b32 v" #r ", 0x7f800000\n\t"   // +inf: min-identity

// Grid (16,16,2) = 512 blocks x 4 waves, 2 blocks/CU.
// R13: NB=4 (128 queries/wave) + K-split 2 -- each 1 KB A-tile feeds FOUR
// MFMAs (0.25 B/pair; halves R12's L2 traffic, the measured binder). Block =
// 2 query-groups x 2 K-halves; K-halves min-combined through 2 KB LDS.
__global__ __launch_bounds__(256, 2) void chamfer_mfma(
    const float* __restrict__ tpl, const float* __restrict__ src,
    const _Float16* __restrict__ arow, float* __restrict__ blocksum,
    float* __restrict__ out) {
    __shared__ float cmb[2][2][4][32];   // [qg][kh][frag][col]
    __shared__ float wsum[4];

    const int tid = threadIdx.x;
    const int wv = tid >> 6, lane = tid & 63;
    const int n = lane & 31, g = lane >> 5;           // B col / K-half group
    const int qg = wv & 1, kh = wv >> 1;              // query-group / K-half
    const int qb = blockIdx.x, batch = blockIdx.y, dir = blockIdx.z;

    const float* qpts = (dir == 0) ? src : tpl;       // dist1: query = source
    const _Float16* abase = arow + ((dir == 0) ? (size_t)0 : (size_t)65536 * 16)
                          + (size_t)batch * 4096 * 16;

    // Four B fragments (frag i -> query qb*256 + qg*128 + i*32 + n) + |p|^2.
    f16x8 bfr[4];
    float p2[4];
    #pragma unroll
    for (int i = 0; i < 4; ++i) {
        const int q = qb * 256 + qg * 128 + i * 32 + n;
        const float* p = qpts + (size_t)(batch * 4096 + q) * 3;
        float px = p[0], py = p[1], pz = p[2];
        p2[i] = fmaf(px, px, fmaf(py, py, pz * pz));
        _Float16 xh = (_Float16)px, yh = (_Float16)py, zh = (_Float16)pz;
        _Float16 xl = (_Float16)(px - (float)xh);
        _Float16 yl = (_Float16)(py - (float)yh);
        _Float16 zl = (_Float16)(pz - (float)zh);
        f16x8 b;
        if (g == 0) {
            b[0] = xh; b[1] = yh; b[2] = zh;
            b[3] = xh; b[4] = yh; b[5] = zh;
            b[6] = xl; b[7] = yl;
        } else {
            b[0] = zl; b[1] = (_Float16)1.0f; b[2] = (_Float16)1.0f;
            b[3] = (_Float16)0.0f; b[4] = (_Float16)0.0f; b[5] = (_Float16)0.0f;
            b[6] = (_Float16)0.0f; b[7] = (_Float16)0.0f;
        }
        bfr[i] = b;
    }

    // This wave's K-half: 64 tiles starting at tile kh*64 (byte off kh*65536).
    int voff = kh * 65536 + n * 32 + g * 16;
    int cnt = 8;                   // 8 iterations x 8 tiles = 64 tiles
    float acc0 = 1e30f, acc1 = 1e30f, acc2 = 1e30f, acc3 = 1e30f;
    float acc4 = 1e30f, acc5 = 1e30f, acc6 = 1e30f, acc7 = 1e30f;
    f16x8 r0, r1, r2, r3, r4, r5, r6, r7;   // ring, allocator-assigned

    asm volatile(
        // zero-C v[160:175] once; B banks v[96:159] to +inf (folded at tile 0)
        ZM(160) ZM(161) ZM(162) ZM(163) ZM(164) ZM(165) ZM(166) ZM(167)
        ZM(168) ZM(169) ZM(170) ZM(171) ZM(172) ZM(173) ZM(174) ZM(175)
        IM(96)  IM(97)  IM(98)  IM(99)  IM(100) IM(101) IM(102) IM(103)
        IM(104) IM(105) IM(106) IM(107) IM(108) IM(109) IM(110) IM(111)
        IM(112) IM(113) IM(114) IM(115) IM(116) IM(117) IM(118) IM(119)
        IM(120) IM(121) IM(122) IM(123) IM(124) IM(125) IM(126) IM(127)
        IM(128) IM(129) IM(130) IM(131) IM(132) IM(133) IM(134) IM(135)
        IM(136) IM(137) IM(138) IM(139) IM(140) IM(141) IM(142) IM(143)
        IM(144) IM(145) IM(146) IM(147) IM(148) IM(149) IM(150) IM(151)
        IM(152) IM(153) IM(154) IM(155) IM(156) IM(157) IM(158) IM(159)
        // prime ring: tiles 0..7 of this K-half
        LD(r0,0) LD(r1,1024) LD(r2,2048) LD(r3,3072)
        "v_add_u32 %[voff], 0x1000, %[voff]\n\t"
        LD(r4,0) LD(r5,1024) LD(r6,2048) LD(r7,3072)
        "v_add_u32 %[voff], 0x1000, %[voff]\n\t"
        // steady loop: 8 tiles/iter; loads target tile+8 (final iter's loads
        // overshoot the K-half by 8 KB -- landing zone is valid ws, never used)
        "L_cham_%=:\n\t"
        TILE_E(r0,0) TILE_O(r1,1024) TILE_E(r2,2048) TILE_O(r3,3072)
        "v_add_u32 %[voff], 0x1000, %[voff]\n\t"
        TILE_E(r4,0) TILE_O(r5,1024) TILE_E(r6,2048) TILE_O(r7,3072)
        "v_add_u32 %[voff], 0x1000, %[voff]\n\t"
        "s_sub_u32 %[cnt], %[cnt], 1\n\t"
        "s_cmp_lg_u32 %[cnt], 0\n\t"
        "s_cbranch_scc1 L_cham_%=\n\t"
        // tile 63 (odd, r7) wrote B banks, not yet folded: drain MFMA, fold
        "s_nop 7\n\t" "s_nop 7\n\t" "s_nop 7\n\t"
        FOLD_B
        "s_waitcnt vmcnt(0)\n\t"   // drain overshoot loads before reg reuse
        : [r0]"=&v"(r0), [r1]"=&v"(r1), [r2]"=&v"(r2), [r3]"=&v"(r3),
          [r4]"=&v"(r4), [r5]"=&v"(r5), [r6]"=&v"(r6), [r7]"=&v"(r7),
          [voff]"+v"(voff), [cnt]"+s"(cnt),
          [acc0]"+v"(acc0), [acc1]"+v"(acc1), [acc2]"+v"(acc2), [acc3]"+v"(acc3),
          [acc4]"+v"(acc4), [acc5]"+v"(acc5), [acc6]"+v"(acc6), [acc7]"+v"(acc7)
        : [bf0]"v"(bfr[0]), [bf1]"v"(bfr[1]), [bf2]"v"(bfr[2]), [bf3]"v"(bfr[3]),
          [sb]"s"(abase)
        : "memory", "scc",
          "v32","v33","v34","v35","v36","v37","v38","v39",
          "v40","v41","v42","v43","v44","v45","v46","v47",
          "v48","v49","v50","v51","v52","v53","v54","v55",
          "v56","v57","v58","v59","v60","v61","v62","v63",
          "v64","v65","v66","v67","v68","v69","v70","v71",
          "v72","v73","v74","v75","v76","v77","v78","v79",
          "v80","v81","v82","v83","v84","v85","v86","v87",
          "v88","v89","v90","v91","v92","v93","v94","v95",
          "v96","v97","v98","v99","v100","v101","v102","v103",
          "v104","v105","v106","v107","v108","v109","v110","v111",
          "v112","v113","v114","v115","v116","v117","v118","v119",
          "v120","v121","v122","v123","v124","v125","v126","v127",
          "v128","v129","v130","v131","v132","v133","v134","v135",
          "v136","v137","v138","v139","v140","v141","v142","v143",
          "v144","v145","v146","v147","v148","v149","v150","v151",
          "v152","v153","v154","v155","v156","v157","v158","v159",
          "v160","v161","v162","v163","v164","v165","v166","v167",
          "v168","v169","v170","v171","v172","v173","v174","v175");

    // Per-frag: acc pair + cross-lane-half fold -> this K-half's per-col min.
    #pragma unroll
    for (int i = 0; i < 4; ++i) {
        float v = fminf(i == 0 ? fminf(acc0, acc1) :
                        i == 1 ? fminf(acc2, acc3) :
                        i == 2 ? fminf(acc4, acc5) : fminf(acc6, acc7), 1e30f);
        v = fminf(v, __shfl_xor(v, 32));
        if (g == 0) cmb[qg][kh][i][n] = v;
    }
    __syncthreads();

    // kh==0 waves combine both K-halves for their query group.
    float s = 0.0f;
    if (kh == 0 && g == 0) {
        #pragma unroll
        for (int i = 0; i < 4; ++i) {
            float m = fminf(cmb[qg][0][i][n], cmb[qg][1][i][n]);
            float d = fmaxf(m + p2[i], 0.0f);          // == min of clamped
            s += sqrtf(d);
        }
        s *= INV_CNT;
    }
    #pragma unroll
    for (int off = 32; off > 0; off >>= 1) s += __shfl_down(s, off);
    if (lane == 0) wsum[wv] = s;
    __syncthreads();
    if (tid == 0) {
        float t = wsum[0] + wsum[1] + wsum[2] + wsum[3];
        if (blocksum) {
            int flat = (blockIdx.z * N_BATCH + blockIdx.y) * 16 + blockIdx.x;
            blocksum[flat] = t;                        // unique slot: no atomics
        } else {
            atomicAdd(out, t);                         // fallback (small ws)
        }
    }
}

// Reduce 512 block sums -> out[0]. Single block, no atomics.
__global__ __launch_bounds__(256) void final_kernel(
    const float* __restrict__ blocksum, float* __restrict__ out) {
    __shared__ float wsum[4];
    float s = 0.0f;
    #pragma unroll
    for (int j = 0; j < NBLK / 256; ++j)
        s += blocksum[j * 256 + threadIdx.x];
    #pragma unroll
    for (int off = 32; off > 0; off >>= 1) s += __shfl_down(s, off);
    if ((threadIdx.x & 63) == 0) wsum[threadIdx.x >> 6] = s;
    __syncthreads();
    if (threadIdx.x == 0) out[0] = wsum[0] + wsum[1] + wsum[2] + wsum[3];
}

extern "C" void kernel_launch(void* const* d_in, const int* in_sizes, int n_in,
                              void* d_out, int out_size, void* d_ws, size_t ws_size,
                              hipStream_t stream) {
    const float* tpl = (const float*)d_in[0];
    const float* src = (const float*)d_in[1];
    float* out = (float*)d_out;
    _Float16* arow = (_Float16*)d_ws;                  // 4 MB
    const bool roomy = ws_size >= AROW_BYTES + SLACK + NBLK * sizeof(float);
    float* blocksum = roomy ? (float*)((char*)d_ws + AROW_BYTES + SLACK) : nullptr;

    hipLaunchKernelGGL(prep_kernel, dim3((2 * N_BATCH * N_PTS) / 256),
                       dim3(256), 0, stream, tpl, src, arow, out);
    dim3 grid(N_PTS / 256, N_BATCH, 2);                // (16, 16, 2) = 512 blocks
    hipLaunchKernelGGL(chamfer_mfma, grid, dim3(256), 0, stream,
                       tpl, src, arow, blocksum, out);
    if (roomy)
        hipLaunchKernelGGL(final_kernel, dim3(1), dim3(256), 0, stream,
                           blocksum, out);
}

// Round 14
// 75.442 us; speedup vs baseline: 1.0576x; 1.0576x over previous
//
#include <hip/hip_runtime.h>

#define N_PTS   4096
#define N_BATCH 16
#define INV_CNT (1.0f / (2.0f * N_BATCH * N_PTS))
#define AROW_BYTES ((size_t)2 * N_BATCH * N_PTS * 16 * 2)   // 4 MB
#define NBLK    512                // main-kernel blocks

typedef _Float16 f16x8  __attribute__((ext_vector_type(8)));

// 32x32x16 f16 MFMA, K-slot packing (split o = oh + ol, p = ph + pl in f16):
//   A-row (opposite point o): [-2oh_x,-2oh_y,-2oh_z, -2ol_x,-2ol_y,-2ol_z,
//                              -2oh_x,-2oh_y | -2oh_z, o2h, o2l, 0...]
//   B-col (query p):          [ph_x,ph_y,ph_z, ph_x,ph_y,ph_z, pl_x,pl_y |
//                              pl_z, 1, 1, 0...]
//   => C = |o|^2 - 2 o.p   (dropped ol.pl ~2^-22; verified R5-R13, absmax 0.0)
// A lane layout: row=l&31, k=(l>>5)*8+j -> one contiguous 16 B load per lane.
__global__ __launch_bounds__(256) void prep_kernel(
    const float* __restrict__ tpl, const float* __restrict__ src,
    _Float16* __restrict__ arow, float* __restrict__ out) {
    int pt = blockIdx.x * 256 + threadIdx.x;          // 0..131071 (T set, then S set)
    if (pt == 0) out[0] = 0.0f;                       // fallback path runs after
    const float* p = (pt < 65536 ? tpl : src) + (size_t)(pt & 65535) * 3;
    float x = p[0], y = p[1], z = p[2];
    float o2 = fmaf(x, x, fmaf(y, y, z * z));
    _Float16 xh = (_Float16)x, yh = (_Float16)y, zh = (_Float16)z;
    _Float16 xl = (_Float16)(x - (float)xh);
    _Float16 yl = (_Float16)(y - (float)yh);
    _Float16 zl = (_Float16)(z - (float)zh);
    _Float16 o2h = (_Float16)o2;
    _Float16 o2l = (_Float16)(o2 - (float)o2h);
    const _Float16 m2 = (_Float16)-2.0f;              // exact power-of-2 scale
    f16x8 v0, v1;
    v0[0] = m2 * xh; v0[1] = m2 * yh; v0[2] = m2 * zh;
    v0[3] = m2 * xl; v0[4] = m2 * yl; v0[5] = m2 * zl;
    v0[6] = m2 * xh; v0[7] = m2 * yh;
    v1[0] = m2 * zh; v1[1] = o2h; v1[2] = o2l;
    v1[3] = (_Float16)0.0f; v1[4] = (_Float16)0.0f; v1[5] = (_Float16)0.0f;
    v1[6] = (_Float16)0.0f; v1[7] = (_Float16)0.0f;
    *(f16x8*)(arow + (size_t)pt * 16)     = v0;
    *(f16x8*)(arow + (size_t)pt * 16 + 8) = v1;
}

// ---- asm blocks. Pinned: D0a=v[32:47] D0b=v[48:63] (frag0 even/odd banks),
//      D1a=v[64:79] D1b=v[80:95] (frag1), zero-C=v[96:111] (zeroed once). ----
#define FD(a,x,y) "v_min3_f32 %[" #a "], v" #x ", v" #y ", %[" #a "]\n\t"
#define FOLD_D0A FD(acc0,32,33) FD(acc1,34,35) FD(acc0,36,37) FD(acc1,38,39) \
                 FD(acc0,40,41) FD(acc1,42,43) FD(acc0,44,45) FD(acc1,46,47)
#define FOLD_D0B FD(acc0,48,49) FD(acc1,50,51) FD(acc0,52,53) FD(acc1,54,55) \
                 FD(acc0,56,57) FD(acc1,58,59) FD(acc0,60,61) FD(acc1,62,63)
#define FOLD_D1A FD(acc2,64,65) FD(acc3,66,67) FD(acc2,68,69) FD(acc3,70,71) \
                 FD(acc2,72,73) FD(acc3,74,75) FD(acc2,76,77) FD(acc3,78,79)
#define FOLD_D1B FD(acc2,80,81) FD(acc3,82,83) FD(acc2,84,85) FD(acc3,86,87) \
                 FD(acc2,88,89) FD(acc3,90,91) FD(acc2,92,93) FD(acc3,94,95)
#define LD(s,off) "global_load_dwordx4 %[" #s "], %[voff], %[sb] offset:" #off "\n\t"
// even tile: write banks a, fold banks b (written 1 tile ago, ~42 cyc: RAW-safe)
#define TILE_E(s,off) "s_waitcnt vmcnt(7)\n\t" \
  "v_mfma_f32_32x32x16_f16 v[32:47], %[" #s "], %[bf0], v[96:111]\n\t" \
  "v_mfma_f32_32x32x16_f16 v[64:79], %[" #s "], %[bf1], v[96:111]\n\t" \
  LD(s,off) FOLD_D0B FOLD_D1B
// odd tile: write banks b, fold banks a
#define TILE_O(s,off) "s_waitcnt vmcnt(7)\n\t" \
  "v_mfma_f32_32x32x16_f16 v[48:63], %[" #s "], %[bf0], v[96:111]\n\t" \
  "v_mfma_f32_32x32x16_f16 v[80:95], %[" #s "], %[bf1], v[96:111]\n\t" \
  LD(s,off) FOLD_D0A FOLD_D1A
#define ZM(r)  "v_mov_b32 v" #r ", 0\n\t"
#define IM(r)  "v_mov_b32 v" #r ", 0x7f800000\n\t"   // +inf: min-identity

// Grid (16,16,2) = 512 blocks x 4 waves, 2 blocks/CU -- R12 body (best: 76.8)
// + R14 XCD-locality swizzle: with round-robin dispatch (XCD = lin%8), map
// lin -> (qb,batch,dir) so each 128 KB A-region's 16 blocks land on ONE XCD
// and each XCD serves only 4 regions (512 KB << 4 MB L2). R13 proved traffic
// isn't the binder; R6/R8's FETCH=4x arow proved L2 thrash (HBM ~900 cyc
// misses that the depth-8 ring can't cover) -- this kills the thrash.
__global__ __launch_bounds__(256, 2) void chamfer_mfma(
    const float* __restrict__ tpl, const float* __restrict__ src,
    const _Float16* __restrict__ arow, float* __restrict__ blocksum,
    float* __restrict__ out) {
    __shared__ float wsum[4];

    const int tid = threadIdx.x;
    const int wv = tid >> 6, lane = tid & 63;
    const int n = lane & 31, g = lane >> 5;           // B col / K-half group
    // --- XCD-locality remap (bijection on [0,512)) ---
    const int lin = blockIdx.x + 16 * (blockIdx.y + 16 * blockIdx.z);
    const int xcd = lin & 7;                          // round-robin heuristic
    const int s_  = lin >> 3;                         // 0..63
    const int qb  = s_ & 15;
    const int region = xcd + 8 * (s_ >> 4);           // 0..31, region -> 1 XCD
    const int batch  = region & 15;
    const int dir    = region >> 4;

    const float* qpts = (dir == 0) ? src : tpl;       // dist1: query = source
    const _Float16* abase = arow + ((dir == 0) ? (size_t)0 : (size_t)65536 * 16)
                          + (size_t)batch * 4096 * 16;

    // Two B fragments (frag i -> query qb*256 + wv*64 + i*32 + n) + |p|^2.
    f16x8 bfr[2];
    float p2[2];
    #pragma unroll
    for (int i = 0; i < 2; ++i) {
        const int q = qb * 256 + wv * 64 + i * 32 + n;
        const float* p = qpts + (size_t)(batch * 4096 + q) * 3;
        float px = p[0], py = p[1], pz = p[2];
        p2[i] = fmaf(px, px, fmaf(py, py, pz * pz));
        _Float16 xh = (_Float16)px, yh = (_Float16)py, zh = (_Float16)pz;
        _Float16 xl = (_Float16)(px - (float)xh);
        _Float16 yl = (_Float16)(py - (float)yh);
        _Float16 zl = (_Float16)(pz - (float)zh);
        f16x8 b;
        if (g == 0) {
            b[0] = xh; b[1] = yh; b[2] = zh;
            b[3] = xh; b[4] = yh; b[5] = zh;
            b[6] = xl; b[7] = yl;
        } else {
            b[0] = zl; b[1] = (_Float16)1.0f; b[2] = (_Float16)1.0f;
            b[3] = (_Float16)0.0f; b[4] = (_Float16)0.0f; b[5] = (_Float16)0.0f;
            b[6] = (_Float16)0.0f; b[7] = (_Float16)0.0f;
        }
        bfr[i] = b;
    }

    int voff = n * 32 + g * 16;    // per-lane byte offset into A region
    int cnt = 16;                  // 16 iterations x 8 tiles = 128 tiles
    float acc0 = 1e30f, acc1 = 1e30f, acc2 = 1e30f, acc3 = 1e30f;
    f16x8 r0, r1, r2, r3, r4, r5, r6, r7;   // ring, allocator-assigned

    asm volatile(
        // zero-C pinned v[96:111] once; odd banks (v48-63, v80-95) to +inf
        ZM(96) ZM(97) ZM(98) ZM(99) ZM(100) ZM(101) ZM(102) ZM(103)
        ZM(104) ZM(105) ZM(106) ZM(107) ZM(108) ZM(109) ZM(110) ZM(111)
        IM(48) IM(49) IM(50) IM(51) IM(52) IM(53) IM(54) IM(55)
        IM(56) IM(57) IM(58) IM(59) IM(60) IM(61) IM(62) IM(63)
        IM(80) IM(81) IM(82) IM(83) IM(84) IM(85) IM(86) IM(87)
        IM(88) IM(89) IM(90) IM(91) IM(92) IM(93) IM(94) IM(95)
        // prime ring: tiles 0..7
        LD(r0,0) LD(r1,1024) LD(r2,2048) LD(r3,3072)
        "v_add_u32 %[voff], 0x1000, %[voff]\n\t"
        LD(r4,0) LD(r5,1024) LD(r6,2048) LD(r7,3072)
        "v_add_u32 %[voff], 0x1000, %[voff]\n\t"
        // steady loop: 8 tiles/iter; loads target tile+8 (last iter's 8 loads
        // land past the region -- never consumed, drained at the end)
        "L_cham_%=:\n\t"
        TILE_E(r0,0) TILE_O(r1,1024) TILE_E(r2,2048) TILE_O(r3,3072)
        "v_add_u32 %[voff], 0x1000, %[voff]\n\t"
        TILE_E(r4,0) TILE_O(r5,1024) TILE_E(r6,2048) TILE_O(r7,3072)
        "v_add_u32 %[voff], 0x1000, %[voff]\n\t"
        "s_sub_u32 %[cnt], %[cnt], 1\n\t"
        "s_cmp_lg_u32 %[cnt], 0\n\t"
        "s_cbranch_scc1 L_cham_%=\n\t"
        // tile 127 (odd) wrote banks b, not yet folded; MFMA drain then fold
        "s_nop 7\n\t" "s_nop 7\n\t" "s_nop 7\n\t"
        FOLD_D0B FOLD_D1B
        "s_waitcnt vmcnt(0)\n\t"   // drain overshoot loads before reg reuse
        : [r0]"=&v"(r0), [r1]"=&v"(r1), [r2]"=&v"(r2), [r3]"=&v"(r3),
          [r4]"=&v"(r4), [r5]"=&v"(r5), [r6]"=&v"(r6), [r7]"=&v"(r7),
          [voff]"+v"(voff), [cnt]"+s"(cnt),
          [acc0]"+v"(acc0), [acc1]"+v"(acc1), [acc2]"+v"(acc2), [acc3]"+v"(acc3)
        : [bf0]"v"(bfr[0]), [bf1]"v"(bfr[1]), [sb]"s"(abase)
        : "memory", "scc",
          "v32","v33","v34","v35","v36","v37","v38","v39",
          "v40","v41","v42","v43","v44","v45","v46","v47",
          "v48","v49","v50","v51","v52","v53","v54","v55",
          "v56","v57","v58","v59","v60","v61","v62","v63",
          "v64","v65","v66","v67","v68","v69","v70","v71",
          "v72","v73","v74","v75","v76","v77","v78","v79",
          "v80","v81","v82","v83","v84","v85","v86","v87",
          "v88","v89","v90","v91","v92","v93","v94","v95",
          "v96","v97","v98","v99","v100","v101","v102","v103",
          "v104","v105","v106","v107","v108","v109","v110","v111");

    // Per-frag: rows split across lane halves; fold, clamp, sqrt.
    float v0 = fminf(acc0, acc1);
    v0 = fminf(v0, __shfl_xor(v0, 32));
    float v1 = fminf(acc2, acc3);
    v1 = fminf(v1, __shfl_xor(v1, 32));
    float d0 = fmaxf(v0 + p2[0], 0.0f);                // == min of clamped
    float d1 = fmaxf(v1 + p2[1], 0.0f);
    float s = (sqrtf(d0) + sqrtf(d1)) * INV_CNT;
    if (g != 0) s = 0.0f;                              // count each query once
    #pragma unroll
    for (int off = 32; off > 0; off >>= 1) s += __shfl_down(s, off);
    if (lane == 0) wsum[wv] = s;
    __syncthreads();
    if (tid == 0) {
        float t = wsum[0] + wsum[1] + wsum[2] + wsum[3];
        if (blocksum) {
            int flat = (dir * N_BATCH + batch) * 16 + qb;   // remapped coords
            blocksum[flat] = t;                        // unique slot: no atomics
        } else {
            atomicAdd(out, t);                         // fallback (small ws)
        }
    }
}

// Reduce 512 block sums -> out[0]. Single block, no atomics.
__global__ __launch_bounds__(256) void final_kernel(
    const float* __restrict__ blocksum, float* __restrict__ out) {
    __shared__ float wsum[4];
    float s = 0.0f;
    #pragma unroll
    for (int j = 0; j < NBLK / 256; ++j)
        s += blocksum[j * 256 + threadIdx.x];
    #pragma unroll
    for (int off = 32; off > 0; off >>= 1) s += __shfl_down(s, off);
    if ((threadIdx.x & 63) == 0) wsum[threadIdx.x >> 6] = s;
    __syncthreads();
    if (threadIdx.x == 0) out[0] = wsum[0] + wsum[1] + wsum[2] + wsum[3];
}

extern "C" void kernel_launch(void* const* d_in, const int* in_sizes, int n_in,
                              void* d_out, int out_size, void* d_ws, size_t ws_size,
                              hipStream_t stream) {
    const float* tpl = (const float*)d_in[0];
    const float* src = (const float*)d_in[1];
    float* out = (float*)d_out;
    _Float16* arow = (_Float16*)d_ws;                  // 4 MB
    // main kernel's ring overshoots the A region by 8 KB: need slack too
    const bool roomy = ws_size >= AROW_BYTES + 8192 + NBLK * sizeof(float);
    float* blocksum = roomy ? (float*)((char*)d_ws + AROW_BYTES + 8192) : nullptr;

    hipLaunchKernelGGL(prep_kernel, dim3((2 * N_BATCH * N_PTS) / 256),
                       dim3(256), 0, stream, tpl, src, arow, out);
    dim3 grid(N_PTS / 256, N_BATCH, 2);                // (16, 16, 2) = 512 blocks
    hipLaunchKernelGGL(chamfer_mfma, grid, dim3(256), 0, stream,
                       tpl, src, arow, blocksum, out);
    if (roomy)
        hipLaunchKernelGGL(final_kernel, dim3(1), dim3(256), 0, stream,
                           blocksum, out);
}

// Round 15
// 74.913 us; speedup vs baseline: 1.0651x; 1.0071x over previous
//
#include <hip/hip_runtime.h>

#define N_PTS   4096
#define N_BATCH 16
#define INV_CNT (1.0f / (2.0f * N_BATCH * N_PTS))
#define AROW_BYTES ((size_t)2 * N_BATCH * N_PTS * 16 * 2)   // 4 MB
#define NBLK    512                // main-kernel blocks

typedef _Float16 f16x8  __attribute__((ext_vector_type(8)));
#define AS1 __attribute__((address_space(1)))
#define AS3 __attribute__((address_space(3)))

// 32x32x16 f16 MFMA, K-slot packing (split o = oh + ol, p = ph + pl in f16):
//   A-row (opposite point o): [-2oh_x,-2oh_y,-2oh_z, -2ol_x,-2ol_y,-2ol_z,
//                              -2oh_x,-2oh_y | -2oh_z, o2h, o2l, 0...]
//   B-col (query p):          [ph_x,ph_y,ph_z, ph_x,ph_y,ph_z, pl_x,pl_y |
//                              pl_z, 1, 1, 0...]
//   => C = |o|^2 - 2 o.p   (dropped ol.pl ~2^-22; verified R5-R14, absmax 0.0)
__global__ __launch_bounds__(256) void prep_kernel(
    const float* __restrict__ tpl, const float* __restrict__ src,
    _Float16* __restrict__ arow, float* __restrict__ out) {
    int pt = blockIdx.x * 256 + threadIdx.x;          // 0..131071 (T set, then S set)
    if (pt == 0) out[0] = 0.0f;                       // fallback path runs after
    const float* p = (pt < 65536 ? tpl : src) + (size_t)(pt & 65535) * 3;
    float x = p[0], y = p[1], z = p[2];
    float o2 = fmaf(x, x, fmaf(y, y, z * z));
    _Float16 xh = (_Float16)x, yh = (_Float16)y, zh = (_Float16)z;
    _Float16 xl = (_Float16)(x - (float)xh);
    _Float16 yl = (_Float16)(y - (float)yh);
    _Float16 zl = (_Float16)(z - (float)zh);
    _Float16 o2h = (_Float16)o2;
    _Float16 o2l = (_Float16)(o2 - (float)o2h);
    const _Float16 m2 = (_Float16)-2.0f;              // exact power-of-2 scale
    f16x8 v0, v1;
    v0[0] = m2 * xh; v0[1] = m2 * yh; v0[2] = m2 * zh;
    v0[3] = m2 * xl; v0[4] = m2 * yl; v0[5] = m2 * zl;
    v0[6] = m2 * xh; v0[7] = m2 * yh;
    v1[0] = m2 * zh; v1[1] = o2h; v1[2] = o2l;
    v1[3] = (_Float16)0.0f; v1[4] = (_Float16)0.0f; v1[5] = (_Float16)0.0f;
    v1[6] = (_Float16)0.0f; v1[7] = (_Float16)0.0f;
    *(f16x8*)(arow + (size_t)pt * 16)     = v0;
    *(f16x8*)(arow + (size_t)pt * 16 + 8) = v1;
}

// ---- asm blocks (chunk-local register state only). Banks: A = v[32:47]
// (frag0) + v[64:79] (frag1); B = v[48:63] + v[80:95]; zero-C = v[96:111],
// re-zeroed per chunk (cheap; avoids cross-asm-block persistence). ----
#define FD(a,x,y) "v_min3_f32 %[" #a "], v" #x ", v" #y ", %[" #a "]\n\t"
#define FOLD_A FD(acc0,32,33) FD(acc1,34,35) FD(acc0,36,37) FD(acc1,38,39) \
               FD(acc0,40,41) FD(acc1,42,43) FD(acc0,44,45) FD(acc1,46,47) \
               FD(acc2,64,65) FD(acc3,66,67) FD(acc2,68,69) FD(acc3,70,71) \
               FD(acc2,72,73) FD(acc3,74,75) FD(acc2,76,77) FD(acc3,78,79)
#define FOLD_B FD(acc0,48,49) FD(acc1,50,51) FD(acc0,52,53) FD(acc1,54,55) \
               FD(acc0,56,57) FD(acc1,58,59) FD(acc0,60,61) FD(acc1,62,63) \
               FD(acc2,80,81) FD(acc3,82,83) FD(acc2,84,85) FD(acc3,86,87) \
               FD(acc2,88,89) FD(acc3,90,91) FD(acc2,92,93) FD(acc3,94,95)
#define MF_A(d) \
  "v_mfma_f32_32x32x16_f16 v[32:47], %[" #d "], %[bf0], v[96:111]\n\t" \
  "v_mfma_f32_32x32x16_f16 v[64:79], %[" #d "], %[bf1], v[96:111]\n\t"
#define MF_B(d) \
  "v_mfma_f32_32x32x16_f16 v[48:63], %[" #d "], %[bf0], v[96:111]\n\t" \
  "v_mfma_f32_32x32x16_f16 v[80:95], %[" #d "], %[bf1], v[96:111]\n\t"
#define DSR(d,off) "ds_read_b128 %[" #d "], %[dsa] offset:" #off "\n\t"
#define WL(n) "s_waitcnt lgkmcnt(" #n ")\n\t"
#define ZM(r) "v_mov_b32 v" #r ", 0\n\t"
#define NOP3 "s_nop 7\n\t" "s_nop 7\n\t" "s_nop 7\n\t"

// Grid (16,16,2) = 512 blocks x 4 waves, 2 blocks/CU. R12 MFMA/fold body,
// but A served from LDS: per 16-tile chunk the block stages 16 KB ONCE
// (global demand /4 -- R14 diagnosis: per-CU vmem return path saturated at
// 8 waves x independent streams); 8 waves then read via ds_read_b128
// (LDS pipe 128 B/cyc, ~120 cyc deterministic latency, depth-4 lgkm ring).
// Raw-asm vmcnt(4)+s_barrier keeps the next chunk's staging in flight
// across the barrier (no m97-style full drain).
__global__ __launch_bounds__(256, 2) void chamfer_mfma(
    const float* __restrict__ tpl, const float* __restrict__ src,
    const _Float16* __restrict__ arow, float* __restrict__ blocksum,
    float* __restrict__ out) {
    __shared__ uint4 sbuf[2][1024];   // 2 x 16 KB chunk buffers
    __shared__ float wsum[4];

    const int tid = threadIdx.x;
    const int wv = tid >> 6, lane = tid & 63;
    const int n = lane & 31, g = lane >> 5;           // B col / K-half group
    // --- XCD-locality remap (bijection on [0,512)) -- kept from R14 ---
    const int lin = blockIdx.x + 16 * (blockIdx.y + 16 * blockIdx.z);
    const int s_  = lin >> 3;
    const int qb  = s_ & 15;
    const int region = (lin & 7) + 8 * (s_ >> 4);     // region -> 1 XCD
    const int batch  = region & 15;
    const int dir    = region >> 4;

    const float* qpts = (dir == 0) ? src : tpl;       // dist1: query = source
    const _Float16* abase = arow + ((dir == 0) ? (size_t)0 : (size_t)65536 * 16)
                          + (size_t)batch * 4096 * 16;

    // Two B fragments (frag i -> query qb*256 + wv*64 + i*32 + n) + |p|^2.
    f16x8 bfr[2];
    float p2[2];
    #pragma unroll
    for (int i = 0; i < 2; ++i) {
        const int q = qb * 256 + wv * 64 + i * 32 + n;
        const float* p = qpts + (size_t)(batch * 4096 + q) * 3;
        float px = p[0], py = p[1], pz = p[2];
        p2[i] = fmaf(px, px, fmaf(py, py, pz * pz));
        _Float16 xh = (_Float16)px, yh = (_Float16)py, zh = (_Float16)pz;
        _Float16 xl = (_Float16)(px - (float)xh);
        _Float16 yl = (_Float16)(py - (float)yh);
        _Float16 zl = (_Float16)(pz - (float)zh);
        f16x8 b;
        if (g == 0) {
            b[0] = xh; b[1] = yh; b[2] = zh;
            b[3] = xh; b[4] = yh; b[5] = zh;
            b[6] = xl; b[7] = yl;
        } else {
            b[0] = zl; b[1] = (_Float16)1.0f; b[2] = (_Float16)1.0f;
            b[3] = (_Float16)0.0f; b[4] = (_Float16)0.0f; b[5] = (_Float16)0.0f;
            b[6] = (_Float16)0.0f; b[7] = (_Float16)0.0f;
        }
        bfr[i] = b;
    }

    const int lane_off = n * 32 + g * 16;
    const unsigned dsa0 = (unsigned)(size_t)((AS3 char*)&sbuf[0][0]) + lane_off;
    const unsigned dsa1 = (unsigned)(size_t)((AS3 char*)&sbuf[1][0]) + lane_off;

    // Wave's staging share: 4 KB of each 16 KB chunk, 4 x 1 KB load_lds.
    const char* gwave = (const char*)abase + wv * 4096 + lane * 16;
    #define STAGE(ch)                                                          \
        {                                                                      \
            const char* gp = gwave + (size_t)(ch) * 16384;                     \
            AS3 char* lp = (AS3 char*)&sbuf[(ch) & 1][0] + wv * 4096;          \
            _Pragma("unroll")                                                  \
            for (int j = 0; j < 4; ++j)                                        \
                __builtin_amdgcn_global_load_lds(                              \
                    (const AS1 unsigned*)(gp + j * 1024),                      \
                    (AS3 unsigned*)(lp + j * 1024), 16, 0, 0);                 \
        }

    float acc0 = 1e30f, acc1 = 1e30f, acc2 = 1e30f, acc3 = 1e30f;
    f16x8 d0, d1, d2, d3;

    STAGE(0)
    #pragma unroll 1
    for (int c = 0; c < 8; ++c) {
        if (c < 7) STAGE(c + 1)
        if (c < 7)
            asm volatile("s_waitcnt vmcnt(4)\n\ts_barrier" ::: "memory");
        else
            asm volatile("s_waitcnt vmcnt(0)\n\ts_barrier" ::: "memory");
        const unsigned dsa = (c & 1) ? dsa1 : dsa0;

        asm volatile(
            ZM(96) ZM(97) ZM(98) ZM(99) ZM(100) ZM(101) ZM(102) ZM(103)
            ZM(104) ZM(105) ZM(106) ZM(107) ZM(108) ZM(109) ZM(110) ZM(111)
            DSR(d0,0) DSR(d1,1024) DSR(d2,2048) DSR(d3,3072)
            // t0 (A banks, no fold; NOP3 protects t1's fold of t0's D)
            WL(3) MF_A(d0) DSR(d0,4096) NOP3
            WL(3) MF_B(d1) DSR(d1,5120)  FOLD_A      // t1
            WL(3) MF_A(d2) DSR(d2,6144)  FOLD_B      // t2
            WL(3) MF_B(d3) DSR(d3,7168)  FOLD_A      // t3
            WL(3) MF_A(d0) DSR(d0,8192)  FOLD_B      // t4
            WL(3) MF_B(d1) DSR(d1,9216)  FOLD_A      // t5
            WL(3) MF_A(d2) DSR(d2,10240) FOLD_B      // t6
            WL(3) MF_B(d3) DSR(d3,11264) FOLD_A      // t7
            WL(3) MF_A(d0) DSR(d0,12288) FOLD_B      // t8
            WL(3) MF_B(d1) DSR(d1,13312) FOLD_A      // t9
            WL(3) MF_A(d2) DSR(d2,14336) FOLD_B      // t10
            WL(3) MF_B(d3) DSR(d3,15360) FOLD_A      // t11
            WL(3) MF_A(d0) FOLD_B                    // t12
            WL(2) MF_B(d1) FOLD_A                    // t13
            WL(1) MF_A(d2) FOLD_B                    // t14
            WL(0) MF_B(d3) FOLD_A                    // t15
            NOP3 FOLD_B                              // tail: t15's D
            : [d0]"=&v"(d0), [d1]"=&v"(d1), [d2]"=&v"(d2), [d3]"=&v"(d3),
              [acc0]"+v"(acc0), [acc1]"+v"(acc1),
              [acc2]"+v"(acc2), [acc3]"+v"(acc3)
            : [bf0]"v"(bfr[0]), [bf1]"v"(bfr[1]), [dsa]"v"(dsa)
            : "memory",
              "v32","v33","v34","v35","v36","v37","v38","v39",
              "v40","v41","v42","v43","v44","v45","v46","v47",
              "v48","v49","v50","v51","v52","v53","v54","v55",
              "v56","v57","v58","v59","v60","v61","v62","v63",
              "v64","v65","v66","v67","v68","v69","v70","v71",
              "v72","v73","v74","v75","v76","v77","v78","v79",
              "v80","v81","v82","v83","v84","v85","v86","v87",
              "v88","v89","v90","v91","v92","v93","v94","v95",
              "v96","v97","v98","v99","v100","v101","v102","v103",
              "v104","v105","v106","v107","v108","v109","v110","v111");

        // all this wave's ds_reads retired (t15 waited lgkmcnt(0)):
        asm volatile("s_barrier" ::: "memory");  // buffer safe to re-stage
    }

    // Per-frag: rows split across lane halves; fold, clamp, sqrt.
    float v0 = fminf(acc0, acc1);
    v0 = fminf(v0, __shfl_xor(v0, 32));
    float v1 = fminf(acc2, acc3);
    v1 = fminf(v1, __shfl_xor(v1, 32));
    float dd0 = fmaxf(v0 + p2[0], 0.0f);               // == min of clamped
    float dd1 = fmaxf(v1 + p2[1], 0.0f);
    float s = (sqrtf(dd0) + sqrtf(dd1)) * INV_CNT;
    if (g != 0) s = 0.0f;                              // count each query once
    #pragma unroll
    for (int off = 32; off > 0; off >>= 1) s += __shfl_down(s, off);
    if (lane == 0) wsum[wv] = s;
    __syncthreads();
    if (tid == 0) {
        float t = wsum[0] + wsum[1] + wsum[2] + wsum[3];
        if (blocksum) {
            int flat = (dir * N_BATCH + batch) * 16 + qb;   // remapped coords
            blocksum[flat] = t;                        // unique slot: no atomics
        } else {
            atomicAdd(out, t);                         // fallback (small ws)
        }
    }
}

// Reduce 512 block sums -> out[0]. Single block, no atomics.
__global__ __launch_bounds__(256) void final_kernel(
    const float* __restrict__ blocksum, float* __restrict__ out) {
    __shared__ float wsum[4];
    float s = 0.0f;
    #pragma unroll
    for (int j = 0; j < NBLK / 256; ++j)
        s += blocksum[j * 256 + threadIdx.x];
    #pragma unroll
    for (int off = 32; off > 0; off >>= 1) s += __shfl_down(s, off);
    if ((threadIdx.x & 63) == 0) wsum[threadIdx.x >> 6] = s;
    __syncthreads();
    if (threadIdx.x == 0) out[0] = wsum[0] + wsum[1] + wsum[2] + wsum[3];
}

extern "C" void kernel_launch(void* const* d_in, const int* in_sizes, int n_in,
                              void* d_out, int out_size, void* d_ws, size_t ws_size,
                              hipStream_t stream) {
    const float* tpl = (const float*)d_in[0];
    const float* src = (const float*)d_in[1];
    float* out = (float*)d_out;
    _Float16* arow = (_Float16*)d_ws;                  // 4 MB
    const bool roomy = ws_size >= AROW_BYTES + NBLK * sizeof(float);
    float* blocksum = roomy ? (float*)((char*)d_ws + AROW_BYTES) : nullptr;

    hipLaunchKernelGGL(prep_kernel, dim3((2 * N_BATCH * N_PTS) / 256),
                       dim3(256), 0, stream, tpl, src, arow, out);
    dim3 grid(N_PTS / 256, N_BATCH, 2);                // (16, 16, 2) = 512 blocks
    hipLaunchKernelGGL(chamfer_mfma, grid, dim3(256), 0, stream,
                       tpl, src, arow, blocksum, out);
    if (roomy)
        hipLaunchKernelGGL(final_kernel, dim3(1), dim3(256), 0, stream,
                           blocksum, out);
}